// Round 2
// baseline (180.336 us; speedup 1.0000x reference)
//
#include <hip/hip_runtime.h>
#include <hip/hip_bf16.h>

#define B_DIM 512
#define D_DIM 256
#define C_DIM 100000
#define LAMB 1000.0f

using bf16x8 = __attribute__((ext_vector_type(8))) short;
using f32x4  = __attribute__((ext_vector_type(4))) float;

__device__ __forceinline__ short f2bf(float f) {
  unsigned u = __builtin_bit_cast(unsigned, f);
  u += 0x7FFFu + ((u >> 16) & 1u);      // round-to-nearest-even
  return (short)(u >> 16);
}

// Kernel 1: xlen per row + linear bf16 copy of x (B-frags read it directly).
__global__ __launch_bounds__(256) void prep_x(const float* __restrict__ x,
                                              unsigned short* __restrict__ xb,
                                              float* __restrict__ xlen) {
  int wv = threadIdx.x >> 6, lane = threadIdx.x & 63;
  int row = blockIdx.x * 4 + wv;
  float4 v = *(const float4*)(x + row * D_DIM + lane * 4);
  float ss = v.x * v.x + v.y * v.y + v.z * v.z + v.w * v.w;
#pragma unroll
  for (int m = 1; m < 64; m <<= 1) ss += __shfl_xor(ss, m);
  if (lane == 0) xlen[row] = sqrtf(ss);
  ushort4 u;
  u.x = (unsigned short)f2bf(v.x);
  u.y = (unsigned short)f2bf(v.y);
  u.z = (unsigned short)f2bf(v.z);
  u.w = (unsigned short)f2bf(v.w);
  *(ushort4*)(xb + row * D_DIM + lane * 4) = u;
}

// Kernel 2: GEMM, no LDS, no barriers. Grid over N only (W read exactly once).
// Block = 4 waves x 32 W-cols. A = W (register-resident bf16 frags),
// B = x (loaded per 16-row j-tile straight from L2-resident bf16 x).
// D layout: col=lane&15 -> x-row, row=(lane>>4)*4+reg -> W-col => float4 store.
__global__ __launch_bounds__(256) void gemm_bf16(
    const float* __restrict__ W, const unsigned short* __restrict__ xb,
    const float* __restrict__ xlen, float* __restrict__ out) {
  const int tid = threadIdx.x;
  const int lane = tid & 63, wv = tid >> 6;
  const int l15 = lane & 15, g = lane >> 4;
  const int bn0 = blockIdx.x * 128 + wv * 32;

  // ---- Phase 1: W cols -> A-frags (bf16) + inv_wlen (fp32) ----
  // A-frag for mfma_f32_16x16x32_bf16: lane holds A[row][k], row = lane&15,
  // k = (lane>>4)*8 + j.
  bf16x8 fw[2][8];
  float invw4[2][4];   // inv_wlen for W-col = bn0 + it*16 + g*4 + r
#pragma unroll
  for (int it = 0; it < 2; ++it) {
    int col = bn0 + it * 16 + l15;
    if (col >= C_DIM) col = C_DIM - 1;        // clamp; stores are guarded
    const float* wr = W + (size_t)col * D_DIM + g * 8;
    float ss = 0.f;
#pragma unroll
    for (int kg = 0; kg < 8; ++kg) {
      float4 a = *(const float4*)(wr + kg * 32);
      float4 b = *(const float4*)(wr + kg * 32 + 4);
      ss += a.x * a.x + a.y * a.y + a.z * a.z + a.w * a.w
          + b.x * b.x + b.y * b.y + b.z * b.z + b.w * b.w;
      bf16x8 f;
      f[0] = f2bf(a.x); f[1] = f2bf(a.y); f[2] = f2bf(a.z); f[3] = f2bf(a.w);
      f[4] = f2bf(b.x); f[5] = f2bf(b.y); f[6] = f2bf(b.z); f[7] = f2bf(b.w);
      fw[it][kg] = f;
    }
    ss += __shfl_xor(ss, 16);                 // reduce across the 4 g-groups
    ss += __shfl_xor(ss, 32);
    float iw = 1.0f / sqrtf(ss);              // valid for col-offset = l15
#pragma unroll
    for (int r = 0; r < 4; ++r) invw4[it][r] = __shfl(iw, g * 4 + r);
  }

  // ---- Main loop: 32 j-tiles of 16 x-rows; B-frags straight from global ----
  for (int jt = 0; jt < 32; ++jt) {
    const int xrow = jt * 16 + l15;           // B col = lane&15 -> x-row
    float xl = xlen[xrow];
    const unsigned short* xp = xb + xrow * D_DIM + g * 8;
    bf16x8 fx[8];
#pragma unroll
    for (int kg = 0; kg < 8; ++kg)
      fx[kg] = *(const bf16x8*)(xp + kg * 32);

    f32x4 acc0 = {}, acc1 = {};
#pragma unroll
    for (int kg = 0; kg < 8; ++kg) {
      acc0 = __builtin_amdgcn_mfma_f32_16x16x32_bf16(fw[0][kg], fx[kg], acc0, 0, 0, 0);
      acc1 = __builtin_amdgcn_mfma_f32_16x16x32_bf16(fw[1][kg], fx[kg], acc1, 0, 0, 0);
    }

    // epilogue: feat = clamp(dot * inv_wlen, -xlen, xlen); float4 stores
#pragma unroll
    for (int it = 0; it < 2; ++it) {
      const f32x4& a = it ? acc1 : acc0;
      int wc = bn0 + it * 16 + g * 4;         // D row = g*4 + r -> W-col
      if (wc < C_DIM) {                       // C%4==0 -> float4 all-or-nothing
        float4 v;
        v.x = fminf(fmaxf(a[0] * invw4[it][0], -xl), xl);
        v.y = fminf(fmaxf(a[1] * invw4[it][1], -xl), xl);
        v.z = fminf(fmaxf(a[2] * invw4[it][2], -xl), xl);
        v.w = fminf(fmaxf(a[3] * invw4[it][3], -xl), xl);
        *(float4*)(out + (size_t)xrow * C_DIM + wc) = v;
      }
    }
  }
}

// Kernel 3: exact fp32 recompute of the 512 label positions (margin math).
__global__ __launch_bounds__(256) void fix_labels(const float* __restrict__ x,
                                                  const float* __restrict__ W,
                                                  const int* __restrict__ y,
                                                  float* __restrict__ out) {
  int wv = threadIdx.x >> 6, lane = threadIdx.x & 63;
  int b = blockIdx.x * 4 + wv;
  int c = y[b];
  float4 wvv = *(const float4*)(W + (size_t)c * D_DIM + lane * 4);
  float4 xv  = *(const float4*)(x + b * D_DIM + lane * 4);
  float dt = wvv.x * xv.x + wvv.y * xv.y + wvv.z * xv.z + wvv.w * xv.w;
  float sw = wvv.x * wvv.x + wvv.y * wvv.y + wvv.z * wvv.z + wvv.w * wvv.w;
  float sx = xv.x * xv.x + xv.y * xv.y + xv.z * xv.z + xv.w * xv.w;
#pragma unroll
  for (int m = 1; m < 64; m <<= 1) {
    dt += __shfl_xor(dt, m);
    sw += __shfl_xor(sw, m);
    sx += __shfl_xor(sx, m);
  }
  if (lane == 0) {
    float xl = sqrtf(sx), wl = sqrtf(sw);
    float cth = dt / (xl * wl);
    cth = fminf(fmaxf(cth, -1.f), 1.f);
    float c2 = cth * cth;
    float cm = 8.f * c2 * c2 - 8.f * c2 + 1.f;          // cos(4t) Chebyshev
    float k = floorf(4.0f * acosf(cth) / 3.14159265358979323846f);
    float sgn = (((int)k) & 1) ? -1.f : 1.f;
    float phi = sgn * cm - 2.f * k;
    float feat = cth * xl;
    out[(size_t)b * C_DIM + c] = feat + (phi * xl - feat) / (1.f + LAMB);
  }
}

extern "C" void kernel_launch(void* const* d_in, const int* in_sizes, int n_in,
                              void* d_out, int out_size, void* d_ws, size_t ws_size,
                              hipStream_t stream) {
  const float* x = (const float*)d_in[0];
  const float* W = (const float*)d_in[1];
  const int*   y = (const int*)d_in[2];
  float* out = (float*)d_out;

  unsigned short* xb = (unsigned short*)d_ws;                    // 256 KB
  float* xlen = (float*)((char*)d_ws + B_DIM * D_DIM * 2);       // 2 KB

  prep_x<<<B_DIM / 4, 256, 0, stream>>>(x, xb, xlen);
  gemm_bf16<<<(C_DIM + 127) / 128, 256, 0, stream>>>(W, xb, xlen, out);
  fix_labels<<<B_DIM / 4, 256, 0, stream>>>(x, W, y, out);
}

// Round 3
// 138.577 us; speedup vs baseline: 1.3013x; 1.3013x over previous
//
#include <hip/hip_runtime.h>
#include <hip/hip_bf16.h>

#define B_DIM 512
#define D_DIM 256
#define C_DIM 100000
#define LAMB 1000.0f

using bf16x8 = __attribute__((ext_vector_type(8))) short;
using f32x4  = __attribute__((ext_vector_type(4))) float;

__device__ __forceinline__ short f2bf(float f) {
  unsigned u = __builtin_bit_cast(unsigned, f);
  u += 0x7FFFu + ((u >> 16) & 1u);      // round-to-nearest-even
  return (short)(u >> 16);
}

// async global->LDS, 16B per lane; LDS dest = wave-uniform base + lane*16
__device__ __forceinline__ void gload_lds16(const void* g, void* l) {
  __builtin_amdgcn_global_load_lds(
      (__attribute__((address_space(1))) void*)g,
      (__attribute__((address_space(3))) void*)l, 16, 0, 0);
}

// Kernel 1: xlen per row + bf16 x, pre-swizzled (byte ^= (row&7)<<4) so the
// GEMM's linear LDS staging + swizzled ds_read_b128 is bank-conflict-minimal.
__global__ __launch_bounds__(256) void prep_x(const float* __restrict__ x,
                                              unsigned short* __restrict__ x_swz,
                                              float* __restrict__ xlen) {
  int wv = threadIdx.x >> 6, lane = threadIdx.x & 63;
  int row = blockIdx.x * 4 + wv;
  float4 v = *(const float4*)(x + row * D_DIM + lane * 4);
  float ss = v.x * v.x + v.y * v.y + v.z * v.z + v.w * v.w;
#pragma unroll
  for (int m = 1; m < 64; m <<= 1) ss += __shfl_xor(ss, m);
  if (lane == 0) xlen[row] = sqrtf(ss);
  ushort4 u;
  u.x = (unsigned short)f2bf(v.x);
  u.y = (unsigned short)f2bf(v.y);
  u.z = (unsigned short)f2bf(v.z);
  u.w = (unsigned short)f2bf(v.w);
  int byteoff = row * 512 + ((lane * 8) ^ ((row & 7) << 4));
  *(ushort4*)((char*)x_swz + byteoff) = u;
}

// Kernel 2: GEMM. Grid over N only (W read exactly once). Block = 4 waves x
// 32 W-cols. A = W (register-resident bf16 frags, 64 VGPR/wave), B = x
// (swizzled bf16, streamed via global_load_lds into 2x16KB LDS, 2-phase
// double buffer). D layout: col=lane&15 -> x-row, row=(lane>>4)*4+reg ->
// W-col => float4 stores.
__global__ __launch_bounds__(256, 4) void gemm_bf16(
    const float* __restrict__ W, const unsigned short* __restrict__ xb,
    const float* __restrict__ xlen, float* __restrict__ out) {
  __shared__ unsigned short xs[2][32 * 256];   // 2 x 16 KB (swizzled rows)
  __shared__ float xlen_s[B_DIM];

  const int tid = threadIdx.x;
  const int lane = tid & 63, wv = tid >> 6;
  const int l15 = lane & 15, g = lane >> 4;
  const int bn0 = blockIdx.x * 128 + wv * 32;

  for (int i = tid; i < B_DIM; i += 256) xlen_s[i] = xlen[i];

  // prologue: stage chunk 0 while we do the long phase-1 W load
#pragma unroll
  for (int i = 0; i < 4; ++i)
    gload_lds16((const char*)xb + i * 4096 + tid * 16,
                (char*)xs[0] + i * 4096 + wv * 1024);

  // ---- Phase 1: W cols -> A-frags (bf16) + inv_wlen (fp32) ----
  // A-frag: lane holds A[row][k], row = lane&15 -> W-col, k = kg*32+g*8+j.
  bf16x8 fw[2][8];
  float invw4[2][4];   // inv_wlen for W-col = bn0 + it*16 + g*4 + r
#pragma unroll
  for (int it = 0; it < 2; ++it) {
    int col = bn0 + it * 16 + l15;
    if (col >= C_DIM) col = C_DIM - 1;        // clamp; stores are guarded
    const float* wr = W + (size_t)col * D_DIM + g * 8;
    float ss = 0.f;
#pragma unroll
    for (int kg = 0; kg < 8; ++kg) {
      float4 a = *(const float4*)(wr + kg * 32);
      float4 b = *(const float4*)(wr + kg * 32 + 4);
      ss += a.x * a.x + a.y * a.y + a.z * a.z + a.w * a.w
          + b.x * b.x + b.y * b.y + b.z * b.z + b.w * b.w;
      bf16x8 f;
      f[0] = f2bf(a.x); f[1] = f2bf(a.y); f[2] = f2bf(a.z); f[3] = f2bf(a.w);
      f[4] = f2bf(b.x); f[5] = f2bf(b.y); f[6] = f2bf(b.z); f[7] = f2bf(b.w);
      fw[it][kg] = f;
    }
    ss += __shfl_xor(ss, 16);                 // reduce across the 4 g-groups
    ss += __shfl_xor(ss, 32);
    float iw = 1.0f / sqrtf(ss);              // lane l15 holds col bn0+it*16+l15
#pragma unroll
    for (int r = 0; r < 4; ++r) invw4[it][r] = __shfl(iw, g * 4 + r);
  }

  __syncthreads();                            // chunk 0 staged (vmcnt drained)

  // ---- Main loop: 16 chunks of 32 x-rows, 2-phase double buffer ----
  int buf = 0;
  for (int chunk = 0; chunk < 16; ++chunk) {
    if (chunk < 15) {                         // stage next chunk first (T3)
#pragma unroll
      for (int i = 0; i < 4; ++i)
        gload_lds16((const char*)xb + (chunk + 1) * 16384 + i * 4096 + tid * 16,
                    (char*)xs[buf ^ 1] + i * 4096 + wv * 1024);
    }

#pragma unroll
    for (int jtl = 0; jtl < 2; ++jtl) {
      const int xrow = chunk * 32 + jtl * 16 + l15;   // B col = lane&15 -> x-row
      const float xl = xlen_s[xrow];
      const char* xp = (const char*)xs[buf] + (jtl * 16 + l15) * 512;
      const int swz = (l15 & 7) << 4;
      bf16x8 fx[8];
#pragma unroll
      for (int kg = 0; kg < 8; ++kg)
        fx[kg] = *(const bf16x8*)(xp + ((kg * 64 + g * 16) ^ swz));

      f32x4 acc0 = {}, acc1 = {};
#pragma unroll
      for (int kg = 0; kg < 8; ++kg) {
        acc0 = __builtin_amdgcn_mfma_f32_16x16x32_bf16(fw[0][kg], fx[kg], acc0, 0, 0, 0);
        acc1 = __builtin_amdgcn_mfma_f32_16x16x32_bf16(fw[1][kg], fx[kg], acc1, 0, 0, 0);
      }

      // epilogue: feat = clamp(dot * inv_wlen, -xlen, xlen); float4 stores
#pragma unroll
      for (int it = 0; it < 2; ++it) {
        const f32x4& a = it ? acc1 : acc0;
        int wc = bn0 + it * 16 + g * 4;       // D row = g*4 + r -> W-col
        if (wc < C_DIM) {                     // C%4==0 -> float4 all-or-nothing
          float4 v;
          v.x = fminf(fmaxf(a[0] * invw4[it][0], -xl), xl);
          v.y = fminf(fmaxf(a[1] * invw4[it][1], -xl), xl);
          v.z = fminf(fmaxf(a[2] * invw4[it][2], -xl), xl);
          v.w = fminf(fmaxf(a[3] * invw4[it][3], -xl), xl);
          *(float4*)(out + (size_t)xrow * C_DIM + wc) = v;
        }
      }
    }

    __syncthreads();                          // next buffer staged; buf free
    buf ^= 1;
  }
}

// Kernel 3: exact fp32 recompute of the 512 label positions (margin math).
__global__ __launch_bounds__(256) void fix_labels(const float* __restrict__ x,
                                                  const float* __restrict__ W,
                                                  const int* __restrict__ y,
                                                  float* __restrict__ out) {
  int wv = threadIdx.x >> 6, lane = threadIdx.x & 63;
  int b = blockIdx.x * 4 + wv;
  int c = y[b];
  float4 wvv = *(const float4*)(W + (size_t)c * D_DIM + lane * 4);
  float4 xv  = *(const float4*)(x + b * D_DIM + lane * 4);
  float dt = wvv.x * xv.x + wvv.y * xv.y + wvv.z * xv.z + wvv.w * xv.w;
  float sw = wvv.x * wvv.x + wvv.y * wvv.y + wvv.z * wvv.z + wvv.w * wvv.w;
  float sx = xv.x * xv.x + xv.y * xv.y + xv.z * xv.z + xv.w * xv.w;
#pragma unroll
  for (int m = 1; m < 64; m <<= 1) {
    dt += __shfl_xor(dt, m);
    sw += __shfl_xor(sw, m);
    sx += __shfl_xor(sx, m);
  }
  if (lane == 0) {
    float xl = sqrtf(sx), wl = sqrtf(sw);
    float cth = dt / (xl * wl);
    cth = fminf(fmaxf(cth, -1.f), 1.f);
    float c2 = cth * cth;
    float cm = 8.f * c2 * c2 - 8.f * c2 + 1.f;          // cos(4t) Chebyshev
    float k = floorf(4.0f * acosf(cth) / 3.14159265358979323846f);
    float sgn = (((int)k) & 1) ? -1.f : 1.f;
    float phi = sgn * cm - 2.f * k;
    float feat = cth * xl;
    out[(size_t)b * C_DIM + c] = feat + (phi * xl - feat) / (1.f + LAMB);
  }
}

extern "C" void kernel_launch(void* const* d_in, const int* in_sizes, int n_in,
                              void* d_out, int out_size, void* d_ws, size_t ws_size,
                              hipStream_t stream) {
  const float* x = (const float*)d_in[0];
  const float* W = (const float*)d_in[1];
  const int*   y = (const int*)d_in[2];
  float* out = (float*)d_out;

  unsigned short* xb = (unsigned short*)d_ws;                    // 256 KB (swizzled bf16 x)
  float* xlen = (float*)((char*)d_ws + B_DIM * D_DIM * 2);       // 2 KB

  prep_x<<<B_DIM / 4, 256, 0, stream>>>(x, xb, xlen);
  gemm_bf16<<<(C_DIM + 127) / 128, 256, 0, stream>>>(W, xb, xlen, out);
  fix_labels<<<B_DIM / 4, 256, 0, stream>>>(x, W, y, out);
}

// Round 4
// 95.527 us; speedup vs baseline: 1.8878x; 1.4507x over previous
//
#include <hip/hip_runtime.h>
#include <hip/hip_bf16.h>

#define B_DIM 512
#define D_DIM 256
#define C_DIM 100000
#define LAMB 1000.0f

using bf16x8 = __attribute__((ext_vector_type(8))) short;
using f32x4  = __attribute__((ext_vector_type(4))) float;

__device__ __forceinline__ short f2bf(float f) {
  unsigned u = __builtin_bit_cast(unsigned, f);
  u += 0x7FFFu + ((u >> 16) & 1u);      // round-to-nearest-even
  return (short)(u >> 16);
}

// async global->LDS, 16B per lane; LDS dest = wave-uniform base + lane*16
__device__ __forceinline__ void gload_lds16(const void* g, void* l) {
  __builtin_amdgcn_global_load_lds(
      (__attribute__((address_space(1))) void*)g,
      (__attribute__((address_space(3))) void*)l, 16, 0, 0);
}

// Kernel 1: xlen per row + bf16 x, pre-swizzled (byte ^= (row&7)<<4) so the
// GEMM's linear LDS staging + swizzled ds_read_b128 is bank-conflict-minimal.
__global__ __launch_bounds__(256) void prep_x(const float* __restrict__ x,
                                              unsigned short* __restrict__ x_swz,
                                              float* __restrict__ xlen) {
  int wv = threadIdx.x >> 6, lane = threadIdx.x & 63;
  int row = blockIdx.x * 4 + wv;
  float4 v = *(const float4*)(x + row * D_DIM + lane * 4);
  float ss = v.x * v.x + v.y * v.y + v.z * v.z + v.w * v.w;
#pragma unroll
  for (int m = 1; m < 64; m <<= 1) ss += __shfl_xor(ss, m);
  if (lane == 0) xlen[row] = sqrtf(ss);
  ushort4 u;
  u.x = (unsigned short)f2bf(v.x);
  u.y = (unsigned short)f2bf(v.y);
  u.z = (unsigned short)f2bf(v.z);
  u.w = (unsigned short)f2bf(v.w);
  int byteoff = row * 512 + ((lane * 8) ^ ((row & 7) << 4));
  *(ushort4*)((char*)x_swz + byteoff) = u;
}

// Kernel 2: GEMM. Grid over N only (W read exactly once). Block = 4 waves x
// 32 W-cols. A = W (register-resident bf16 frags, 64 VGPR/wave), B = x
// (swizzled bf16, streamed via global_load_lds into 2x16KB LDS, 2-phase
// double buffer). D layout: col=lane&15 -> x-row, row=(lane>>4)*4+reg ->
// W-col => float4 stores.
// NOTE: plain launch_bounds(256). (256,4) capped VGPR at 64 -> fw[] spilled
// to scratch -> MfmaUtil 0.25%, 145us. The allocator needs ~120 VGPRs.
__global__ __launch_bounds__(256) void gemm_bf16(
    const float* __restrict__ W, const unsigned short* __restrict__ xb,
    const float* __restrict__ xlen, float* __restrict__ out) {
  __shared__ unsigned short xs[2][32 * 256];   // 2 x 16 KB (swizzled rows)
  __shared__ float xlen_s[B_DIM];

  const int tid = threadIdx.x;
  const int lane = tid & 63, wv = tid >> 6;
  const int l15 = lane & 15, g = lane >> 4;
  const int bn0 = blockIdx.x * 128 + wv * 32;

  for (int i = tid; i < B_DIM; i += 256) xlen_s[i] = xlen[i];

  // prologue: stage chunk 0 while we do the long phase-1 W load
#pragma unroll
  for (int i = 0; i < 4; ++i)
    gload_lds16((const char*)xb + i * 4096 + tid * 16,
                (char*)xs[0] + i * 4096 + wv * 1024);

  // ---- Phase 1: W cols -> A-frags (bf16) + inv_wlen (fp32) ----
  // A-frag: lane holds A[row][k], row = lane&15 -> W-col, k = kg*32+g*8+j.
  bf16x8 fw[2][8];
  float invw4[2][4];   // inv_wlen for W-col = bn0 + it*16 + g*4 + r
#pragma unroll
  for (int it = 0; it < 2; ++it) {
    int col = bn0 + it * 16 + l15;
    if (col >= C_DIM) col = C_DIM - 1;        // clamp; stores are guarded
    const float* wr = W + (size_t)col * D_DIM + g * 8;
    float ss = 0.f;
#pragma unroll
    for (int kg = 0; kg < 8; ++kg) {
      float4 a = *(const float4*)(wr + kg * 32);
      float4 b = *(const float4*)(wr + kg * 32 + 4);
      ss += a.x * a.x + a.y * a.y + a.z * a.z + a.w * a.w
          + b.x * b.x + b.y * b.y + b.z * b.z + b.w * b.w;
      bf16x8 f;
      f[0] = f2bf(a.x); f[1] = f2bf(a.y); f[2] = f2bf(a.z); f[3] = f2bf(a.w);
      f[4] = f2bf(b.x); f[5] = f2bf(b.y); f[6] = f2bf(b.z); f[7] = f2bf(b.w);
      fw[it][kg] = f;
    }
    ss += __shfl_xor(ss, 16);                 // reduce across the 4 g-groups
    ss += __shfl_xor(ss, 32);
    float iw = 1.0f / sqrtf(ss);              // lane l15 holds col bn0+it*16+l15
#pragma unroll
    for (int r = 0; r < 4; ++r) invw4[it][r] = __shfl(iw, g * 4 + r);
  }

  __syncthreads();                            // chunk 0 staged (vmcnt drained)

  // ---- Main loop: 16 chunks of 32 x-rows, 2-phase double buffer ----
  int buf = 0;
  for (int chunk = 0; chunk < 16; ++chunk) {
    if (chunk < 15) {                         // stage next chunk first (T3)
#pragma unroll
      for (int i = 0; i < 4; ++i)
        gload_lds16((const char*)xb + (chunk + 1) * 16384 + i * 4096 + tid * 16,
                    (char*)xs[buf ^ 1] + i * 4096 + wv * 1024);
    }

#pragma unroll
    for (int jtl = 0; jtl < 2; ++jtl) {
      const int xrow = chunk * 32 + jtl * 16 + l15;   // B col = lane&15 -> x-row
      const float xl = xlen_s[xrow];
      const char* xp = (const char*)xs[buf] + (jtl * 16 + l15) * 512;
      const int swz = (l15 & 7) << 4;
      bf16x8 fx[8];
#pragma unroll
      for (int kg = 0; kg < 8; ++kg)
        fx[kg] = *(const bf16x8*)(xp + ((kg * 64 + g * 16) ^ swz));

      f32x4 acc0 = {}, acc1 = {};
#pragma unroll
      for (int kg = 0; kg < 8; ++kg) {
        acc0 = __builtin_amdgcn_mfma_f32_16x16x32_bf16(fw[0][kg], fx[kg], acc0, 0, 0, 0);
        acc1 = __builtin_amdgcn_mfma_f32_16x16x32_bf16(fw[1][kg], fx[kg], acc1, 0, 0, 0);
      }

      // epilogue: feat = clamp(dot * inv_wlen, -xlen, xlen); float4 stores
#pragma unroll
      for (int it = 0; it < 2; ++it) {
        const f32x4& a = it ? acc1 : acc0;
        int wc = bn0 + it * 16 + g * 4;       // D row = g*4 + r -> W-col
        if (wc < C_DIM) {                     // C%4==0 -> float4 all-or-nothing
          float4 v;
          v.x = fminf(fmaxf(a[0] * invw4[it][0], -xl), xl);
          v.y = fminf(fmaxf(a[1] * invw4[it][1], -xl), xl);
          v.z = fminf(fmaxf(a[2] * invw4[it][2], -xl), xl);
          v.w = fminf(fmaxf(a[3] * invw4[it][3], -xl), xl);
          *(float4*)(out + (size_t)xrow * C_DIM + wc) = v;
        }
      }
    }

    __syncthreads();                          // next buffer staged; buf free
    buf ^= 1;
  }
}

// Kernel 3: exact fp32 recompute of the 512 label positions (margin math).
__global__ __launch_bounds__(256) void fix_labels(const float* __restrict__ x,
                                                  const float* __restrict__ W,
                                                  const int* __restrict__ y,
                                                  float* __restrict__ out) {
  int wv = threadIdx.x >> 6, lane = threadIdx.x & 63;
  int b = blockIdx.x * 4 + wv;
  int c = y[b];
  float4 wvv = *(const float4*)(W + (size_t)c * D_DIM + lane * 4);
  float4 xv  = *(const float4*)(x + b * D_DIM + lane * 4);
  float dt = wvv.x * xv.x + wvv.y * xv.y + wvv.z * xv.z + wvv.w * xv.w;
  float sw = wvv.x * wvv.x + wvv.y * wvv.y + wvv.z * wvv.z + wvv.w * wvv.w;
  float sx = xv.x * xv.x + xv.y * xv.y + xv.z * xv.z + xv.w * xv.w;
#pragma unroll
  for (int m = 1; m < 64; m <<= 1) {
    dt += __shfl_xor(dt, m);
    sw += __shfl_xor(sw, m);
    sx += __shfl_xor(sx, m);
  }
  if (lane == 0) {
    float xl = sqrtf(sx), wl = sqrtf(sw);
    float cth = dt / (xl * wl);
    cth = fminf(fmaxf(cth, -1.f), 1.f);
    float c2 = cth * cth;
    float cm = 8.f * c2 * c2 - 8.f * c2 + 1.f;          // cos(4t) Chebyshev
    float k = floorf(4.0f * acosf(cth) / 3.14159265358979323846f);
    float sgn = (((int)k) & 1) ? -1.f : 1.f;
    float phi = sgn * cm - 2.f * k;
    float feat = cth * xl;
    out[(size_t)b * C_DIM + c] = feat + (phi * xl - feat) / (1.f + LAMB);
  }
}

extern "C" void kernel_launch(void* const* d_in, const int* in_sizes, int n_in,
                              void* d_out, int out_size, void* d_ws, size_t ws_size,
                              hipStream_t stream) {
  const float* x = (const float*)d_in[0];
  const float* W = (const float*)d_in[1];
  const int*   y = (const int*)d_in[2];
  float* out = (float*)d_out;

  unsigned short* xb = (unsigned short*)d_ws;                    // 256 KB (swizzled bf16 x)
  float* xlen = (float*)((char*)d_ws + B_DIM * D_DIM * 2);       // 2 KB

  prep_x<<<B_DIM / 4, 256, 0, stream>>>(x, xb, xlen);
  gemm_bf16<<<(C_DIM + 127) / 128, 256, 0, stream>>>(W, xb, xlen, out);
  fix_labels<<<B_DIM / 4, 256, 0, stream>>>(x, W, y, out);
}